// Round 1
// baseline (253.282 us; speedup 1.0000x reference)
//
#include <hip/hip_runtime.h>

#define MROWS 16384
#define NCOLS 256
#define NV4   (NCOLS / 4)   // 64 float4 per row

// ---------------- K1: zero the per-row counters ----------------
__global__ void k_zero(int* __restrict__ cnt, int n) {
    int t = blockIdx.x * blockDim.x + threadIdx.x;
    if (t < n) cnt[t] = 0;
}

// ---------------- K2: histogram of rows ----------------
__global__ void k_hist(const int* __restrict__ rows, int* __restrict__ cnt, int nnz) {
    int t = blockIdx.x * blockDim.x + threadIdx.x;
    if (t < nnz) atomicAdd(&cnt[rows[t]], 1);
}

// ---------------- K3: exclusive scan of counts -> row_start, cursor ----------------
__global__ __launch_bounds__(1024) void k_scan(const int* __restrict__ cnt,
                                               int* __restrict__ row_start,
                                               int* __restrict__ cursor) {
    __shared__ int partial[1024];
    const int tid = threadIdx.x;
    const int PER = MROWS / 1024;  // 16
    int local[PER];
    int sum = 0;
#pragma unroll
    for (int k = 0; k < PER; ++k) {
        local[k] = sum;
        sum += cnt[tid * PER + k];
    }
    partial[tid] = sum;
    __syncthreads();
    // Hillis-Steele inclusive scan over 1024 partials
    for (int off = 1; off < 1024; off <<= 1) {
        int v = 0;
        if (tid >= off) v = partial[tid - off];
        __syncthreads();
        if (tid >= off) partial[tid] += v;
        __syncthreads();
    }
    int base = (tid == 0) ? 0 : partial[tid - 1];
#pragma unroll
    for (int k = 0; k < PER; ++k) {
        int v = base + local[k];
        row_start[tid * PER + k] = v;
        cursor[tid * PER + k]    = v;
    }
    if (tid == 1023) row_start[MROWS] = base + sum;  // == total nnz
}

// ---------------- K4: scatter nnz into row-sorted order ----------------
__global__ void k_scatter(const float* __restrict__ values, const int* __restrict__ rows,
                          const int* __restrict__ cols, int* __restrict__ cursor,
                          float* __restrict__ sval, int* __restrict__ scol, int nnz) {
    int t = blockIdx.x * blockDim.x + threadIdx.x;
    if (t < nnz) {
        int r   = rows[t];
        int pos = atomicAdd(&cursor[r], 1);
        sval[pos] = values[t];
        scol[pos] = cols[t];
    }
}

// ---------------- K5: per-row gather-accumulate + add input ----------------
// One wave (64 lanes) per output row; each lane owns 4 columns as float4.
__global__ __launch_bounds__(256) void k_spmm(const float4* __restrict__ in4,
                                              const float* __restrict__ sval,
                                              const int* __restrict__ scol,
                                              const int* __restrict__ row_start,
                                              const float4* __restrict__ dense4,
                                              float4* __restrict__ out4) {
    const int wave = threadIdx.x >> 6;
    const int lane = threadIdx.x & 63;
    const int row  = blockIdx.x * 4 + wave;

    int s = row_start[row];
    int e = row_start[row + 1];
    s = __builtin_amdgcn_readfirstlane(s);   // wave-uniform -> scalar loop
    e = __builtin_amdgcn_readfirstlane(e);

    float ax = 0.f, ay = 0.f, az = 0.f, aw = 0.f;

    int i = s;
    // unroll-4: 4 independent float4 gathers in flight per iteration
    for (; i + 4 <= e; i += 4) {
        float v0 = sval[i + 0], v1 = sval[i + 1], v2 = sval[i + 2], v3 = sval[i + 3];
        int   c0 = scol[i + 0], c1 = scol[i + 1], c2 = scol[i + 2], c3 = scol[i + 3];
        float4 d0 = dense4[c0 * NV4 + lane];
        float4 d1 = dense4[c1 * NV4 + lane];
        float4 d2 = dense4[c2 * NV4 + lane];
        float4 d3 = dense4[c3 * NV4 + lane];
        ax += v0 * d0.x; ay += v0 * d0.y; az += v0 * d0.z; aw += v0 * d0.w;
        ax += v1 * d1.x; ay += v1 * d1.y; az += v1 * d1.z; aw += v1 * d1.w;
        ax += v2 * d2.x; ay += v2 * d2.y; az += v2 * d2.z; aw += v2 * d2.w;
        ax += v3 * d3.x; ay += v3 * d3.y; az += v3 * d3.z; aw += v3 * d3.w;
    }
    for (; i < e; ++i) {
        float v  = sval[i];
        int   c  = scol[i];
        float4 d = dense4[c * NV4 + lane];
        ax += v * d.x; ay += v * d.y; az += v * d.z; aw += v * d.w;
    }

    const int o = row * NV4 + lane;
    float4 iv = in4[o];
    float4 r;
    r.x = iv.x + ax; r.y = iv.y + ay; r.z = iv.z + az; r.w = iv.w + aw;
    out4[o] = r;
}

// ---------------- Fallback path (if ws too small): copy + atomic scatter ----------------
__global__ void k_copy4(const float4* __restrict__ in4, float4* __restrict__ out4, int n4) {
    int t = blockIdx.x * blockDim.x + threadIdx.x;
    if (t < n4) out4[t] = in4[t];
}

__global__ void k_atomic(const float* __restrict__ values, const int* __restrict__ rows,
                         const int* __restrict__ cols, const float4* __restrict__ dense4,
                         float* __restrict__ out, int nnz) {
    long long t = (long long)blockIdx.x * blockDim.x + threadIdx.x;
    long long total = (long long)nnz * 64;
    if (t >= total) return;
    int i   = (int)(t >> 6);
    int seg = (int)(t & 63);
    float v  = values[i];
    float4 d = dense4[cols[i] * NV4 + seg];
    float* o = out + (size_t)rows[i] * NCOLS + seg * 4;
    atomicAdd(o + 0, v * d.x);
    atomicAdd(o + 1, v * d.y);
    atomicAdd(o + 2, v * d.z);
    atomicAdd(o + 3, v * d.w);
}

extern "C" void kernel_launch(void* const* d_in, const int* in_sizes, int n_in,
                              void* d_out, int out_size, void* d_ws, size_t ws_size,
                              hipStream_t stream) {
    const float* input_mat = (const float*)d_in[0];
    const float* values    = (const float*)d_in[1];
    const int*   rows      = (const int*)d_in[2];
    const int*   cols      = (const int*)d_in[3];
    const float* dense     = (const float*)d_in[4];
    float*       out       = (float*)d_out;

    const int nnz = in_sizes[1];

    // workspace layout
    const size_t off_cursor = 0;                       // MROWS ints
    const size_t off_rs     = (size_t)MROWS * 4;       // (MROWS+1) ints
    const size_t off_sval   = off_rs + ((size_t)MROWS + 1) * 4 + 252;  // round up
    const size_t off_sval_a = (off_sval / 256) * 256;
    const size_t off_scol   = off_sval_a + (size_t)nnz * 4;
    const size_t need       = off_scol + (size_t)nnz * 4;

    char* ws = (char*)d_ws;

    if (ws_size >= need) {
        int*   cursor    = (int*)(ws + off_cursor);
        int*   row_start = (int*)(ws + off_rs);
        float* sval      = (float*)(ws + off_sval_a);
        int*   scol      = (int*)(ws + off_scol);

        k_zero<<<(MROWS + 255) / 256, 256, 0, stream>>>(cursor, MROWS);
        k_hist<<<(nnz + 255) / 256, 256, 0, stream>>>(rows, cursor, nnz);
        k_scan<<<1, 1024, 0, stream>>>(cursor, row_start, cursor);
        k_scatter<<<(nnz + 255) / 256, 256, 0, stream>>>(values, rows, cols, cursor,
                                                         sval, scol, nnz);
        k_spmm<<<MROWS / 4, 256, 0, stream>>>((const float4*)input_mat, sval, scol,
                                              row_start, (const float4*)dense,
                                              (float4*)out);
    } else {
        // fallback: atomic scatter (slow but needs no scratch)
        const int n4 = MROWS * NV4;
        k_copy4<<<(n4 + 255) / 256, 256, 0, stream>>>((const float4*)input_mat,
                                                      (float4*)out, n4);
        long long total = (long long)nnz * 64;
        int blocks = (int)((total + 255) / 256);
        k_atomic<<<blocks, 256, 0, stream>>>(values, rows, cols, (const float4*)dense,
                                             out, nnz);
    }
}